// Round 3
// baseline (422.472 us; speedup 1.0000x reference)
//
#include <hip/hip_runtime.h>
#include <hip/hip_bf16.h>
#include <cstdio>

typedef __bf16 bf16_t;
typedef __attribute__((ext_vector_type(8))) __bf16 bf16x8;
typedef __attribute__((ext_vector_type(4))) __bf16 bf16x4;
typedef __attribute__((ext_vector_type(2))) __bf16 bf16x2;
typedef __attribute__((ext_vector_type(4))) float f32x4;
typedef __attribute__((ext_vector_type(16))) float f32x16;
typedef unsigned int u32;

#define SCALE 0.17677669529663687f   // 32^-0.5
#define NWIN 294                     // 6*7*7

__device__ __forceinline__ void gload16(const void* g, void* l) {
  __builtin_amdgcn_global_load_lds(
      (const __attribute__((address_space(1))) void*)g,
      (__attribute__((address_space(3))) void*)l, 16, 0, 0);
}

__device__ __forceinline__ u32 pk2(float a, float b) {
  bf16x2 t = {(bf16_t)a, (bf16_t)b};
  return __builtin_bit_cast(u32, t);
}

// half-swap: o0 = [a(lo lanes) | b(lo lanes)], o1 = [a(hi lanes) | b(hi lanes)]
__device__ __forceinline__ void pswap(u32 a, u32 b, u32& o0, u32& o1) {
#if __has_builtin(__builtin_amdgcn_permlane32_swap)
  auto r = __builtin_amdgcn_permlane32_swap(a, b, false, false);
  o0 = (u32)r[0]; o1 = (u32)r[1];
#else
  u32 xa = (u32)__shfl_xor((int)a, 32);
  u32 xb = (u32)__shfl_xor((int)b, 32);
  bool hi = (threadIdx.x & 32) != 0;
  o0 = hi ? xb : a;
  o1 = hi ? b : xa;
#endif
}

// ---------------- K0a: convert weights to bf16 ----------------
__global__ void cvt_weights(const float* __restrict__ wq, const float* __restrict__ wo,
                            bf16_t* __restrict__ wqb, bf16_t* __restrict__ wob) {
  int t = blockIdx.x * 256 + threadIdx.x;
  const int nq4 = 768 * 256 / 4;
  if (t < nq4) {
    float4 v = ((const float4*)wq)[t];
    bf16x4 h = {(bf16_t)v.x, (bf16_t)v.y, (bf16_t)v.z, (bf16_t)v.w};
    ((bf16x4*)wqb)[t] = h;
  } else {
    int t2 = t - nq4;
    float4 v = ((const float4*)wo)[t2];
    bf16x4 h = {(bf16_t)v.x, (bf16_t)v.y, (bf16_t)v.z, (bf16_t)v.w};
    ((bf16x4*)wob)[t2] = h;
  }
}

// ---------------- K0b: bias in 32x32 S^T-fragment layout ----------------
// biasf[h][s][j][lane][r]: value = bias[q = s*32+(lane&31)][k = j*32+(r&3)+8*(r>>2)+4*(lane>>5)]
// col>=294 -> -1e30 (mask), row>=294 -> 0.
__global__ void bias_kernel(const float* __restrict__ bt, const int* __restrict__ ridx,
                            bf16_t* __restrict__ biasf) {
  int t = blockIdx.x * 256 + threadIdx.x;
  if (t >= 8 * 10 * 10 * 64 * 16) return;
  int r = t & 15, lane = (t >> 4) & 63;
  int rest = t >> 10;
  int j = rest % 10; rest /= 10;
  int s = rest % 10; int hh = rest / 10;
  int row = s * 32 + (lane & 31);
  int col = j * 32 + (r & 3) + 8 * (r >> 2) + 4 * (lane >> 5);
  float v;
  if (col >= 294)      v = -1e30f;
  else if (row >= 294) v = 0.f;
  else                 v = bt[ridx[row * 294 + col] * 8 + hh];
  biasf[t] = (bf16_t)v;
}

// ---------------- K1: QKV GEMM (unchanged) ----------------
__global__ __launch_bounds__(256, 2)
void qkv_gemm(const float* __restrict__ x, const bf16_t* __restrict__ wqb,
              bf16_t* __restrict__ qkv) {
  __shared__ bf16_t As[2][128][64];
  __shared__ bf16_t Bs[2][128][64];
  const int tid = threadIdx.x;
  const int lane = tid & 63;
  const int w = tid >> 6;
  const int mt = blockIdx.x / 6, nt = blockIdx.x % 6;
  const int m0 = mt * 128, n0 = nt * 128;
  const int rsub = tid >> 4, csub = (tid & 15) * 4;

  const float* asrc[8];
#pragma unroll
  for (int i = 0; i < 8; ++i) {
    int R = m0 + i * 16 + rsub;
    int b_ = R / 294, n = R - b_ * 294;
    int l = n / 49, p = n - l * 49;
    int X = b_ >> 4, Y = b_ & 15;
    int srow = ((l * 16 + X) * 16 + Y) * 49 + p;
    asrc[i] = x + (size_t)srow * 256 + csub;
  }

  const f32x4 zero4 = {0.f, 0.f, 0.f, 0.f};
  f32x4 acc[4][4];
#pragma unroll
  for (int i = 0; i < 4; ++i)
#pragma unroll
    for (int j = 0; j < 4; ++j) acc[i][j] = zero4;

  auto stageA = [&](int buf, int kk) {
    const int k0 = kk * 64;
#pragma unroll
    for (int i = 0; i < 8; ++i) {
      float4 v = *(const float4*)(asrc[i] + k0);
      bf16x4 h = {(bf16_t)v.x, (bf16_t)v.y, (bf16_t)v.z, (bf16_t)v.w};
      *(bf16x4*)&As[buf][i * 16 + rsub][csub] = h;
    }
  };
  auto stageB = [&](int buf, int kk) {
    const int k0 = kk * 64;
#pragma unroll
    for (int i = 0; i < 4; ++i) {
      int row = w * 32 + i * 8;
      const bf16_t* g = wqb + (size_t)(n0 + row + (lane >> 3)) * 256 + k0 + (lane & 7) * 8;
      gload16(g, &Bs[buf][row][0]);
    }
  };
  auto compute = [&](int buf) {
    const int mb = (w >> 1) * 64, nb = (w & 1) * 64;
#pragma unroll
    for (int ks = 0; ks < 2; ++ks) {
      bf16x8 a[4], bb[4];
#pragma unroll
      for (int i = 0; i < 4; ++i)
        a[i] = *(const bf16x8*)&As[buf][mb + i * 16 + (lane & 15)][ks * 32 + (lane >> 4) * 8];
#pragma unroll
      for (int i = 0; i < 4; ++i)
        bb[i] = *(const bf16x8*)&Bs[buf][nb + i * 16 + (lane & 15)][ks * 32 + (lane >> 4) * 8];
#pragma unroll
      for (int i = 0; i < 4; ++i)
#pragma unroll
        for (int j = 0; j < 4; ++j)
          acc[i][j] = __builtin_amdgcn_mfma_f32_16x16x32_bf16(a[i], bb[j], acc[i][j], 0, 0, 0);
    }
  };

  stageA(0, 0); stageB(0, 0);
  __syncthreads();
#pragma unroll
  for (int kk = 0; kk < 4; ++kk) {
    int cur = kk & 1;
    if (kk < 3) { stageA(cur ^ 1, kk + 1); stageB(cur ^ 1, kk + 1); }
    compute(cur);
    __syncthreads();
  }

  const int mb = (w >> 1) * 64, nb = (w & 1) * 64;
#pragma unroll
  for (int i = 0; i < 4; ++i)
#pragma unroll
    for (int r = 0; r < 4; ++r) {
      int row = m0 + mb + i * 16 + (lane >> 4) * 4 + r;
      size_t rb = (size_t)row * 768;
#pragma unroll
      for (int j = 0; j < 4; ++j) {
        int col = n0 + nb + j * 16 + (lane & 15);
        float sc = (col < 256) ? SCALE : 1.0f;
        qkv[rb + col] = (bf16_t)(acc[i][j][r] * sc);
      }
    }
}

// ---------------- K2: attention, 32x32 MFMA, in-register P ----------------
// LDS: Kf slots 0..19 (slot = j*2+c): lane l holds K[j*32+(l&31)][c*16+(l>>5)*8+e], 16B/lane
//      Vf slots 0..19 (slot = k>>4):  lane l holds V[slot*16+(l>>5)*8+e][d=l&31], 16B/lane
__global__ __launch_bounds__(320, 5)
void attn_kernel(const bf16_t* __restrict__ qkv, const bf16_t* __restrict__ biasf,
                 bf16_t* __restrict__ aout) {
  __shared__ uint4 SMEM4[2560];   // 40960 B
  char* KB = (char*)SMEM4;
  char* VB = KB + 20480;
  const int tid = threadIdx.x, lane = tid & 63, wv = tid >> 6;
  const int h = lane >> 5;
  const int b_ = blockIdx.x >> 3, hh = blockIdx.x & 7;
  const size_t qbase = (size_t)b_ * 294 * 768;
  const uint4 z4 = {0u, 0u, 0u, 0u};

  // ---- zero pads (bytes disjoint from staged bytes) ----
  // K slots 18,19: lanes with (l&31) >= 6  (rows 294..319)
  for (int i = tid; i < 104; i += 320) {
    int sl = 18 + (i >= 52), l2 = i % 52;
    int ln = (l2 < 26) ? (6 + l2) : (38 + (l2 - 26));
    *(uint4*)(KB + sl * 1024 + ln * 16) = z4;
  }
  // V slot 19 full; slot 18 lanes 32..63 full
  for (int i = tid; i < 96; i += 320) {
    int sl = (i < 64) ? 19 : 18;
    int ln = (i < 64) ? i : (32 + (i - 64));
    *(uint4*)(VB + sl * 1024 + ln * 16) = z4;
  }
  // V slot 18 lanes 0..31, bytes 12..15 (k=294,295 -> e=6,7)
  for (int i = tid; i < 32; i += 320)
    *(u32*)(VB + 18 * 1024 + i * 16 + 12) = 0u;

  // ---- stage K via global_load_lds (lane-linear dest) ----
#pragma unroll
  for (int it = 0; it < 4; ++it) {
    int sl = wv * 4 + it;          // wave-uniform
    int j = sl >> 1, c = sl & 1;
    int krow = j * 32 + (lane & 31);
    int q4 = c * 2 + h;
    if (krow < 294)
      gload16(qkv + qbase + (size_t)krow * 768 + 256 + hh * 32 + q4 * 8, KB + sl * 1024);
  }
  // ---- stage V (transpose scatter, one-time) ----
  for (int idx = tid; idx < 1176; idx += 320) {   // 294 rows * 4 chunks
    int k = idx >> 2, q4 = idx & 3;
    uint4 v = *(const uint4*)(qkv + qbase + (size_t)k * 768 + 512 + hh * 32 + q4 * 8);
    const unsigned short* pv = (const unsigned short*)&v;
    int sl = k >> 4;
    char* base = VB + sl * 1024 + ((((k >> 3) & 1) * 32 + q4 * 8) * 16) + (k & 7) * 2;
#pragma unroll
    for (int t = 0; t < 8; ++t)
      *(unsigned short*)(base + t * 16) = pv[t];
  }
  __syncthreads();

  const f32x16 zero16 = {0.f};
  for (int s = wv; s < 10; s += 5) {
    // Q fragment (B-operand): rows s*32..+31, zeroed past 294
    int qrow = s * 32 + (lane & 31);
    bf16x8 qf0 = __builtin_bit_cast(bf16x8, z4), qf1 = qf0;
    if (qrow < 294) {
      const bf16_t* qp = qkv + qbase + (size_t)qrow * 768 + hh * 32 + h * 8;
      qf0 = *(const bf16x8*)qp;
      qf1 = *(const bf16x8*)(qp + 16);
    }

    f32x16 oacc = zero16;
    float rowsum = 0.f;
    const bf16_t* bbase = biasf + (size_t)(((hh * 10 + s) * 10) * 64 + lane) * 16;

#pragma unroll
    for (int j = 0; j < 10; ++j) {
      bf16x8 kf0 = *(const bf16x8*)(KB + (j * 2 + 0) * 1024 + lane * 16);
      bf16x8 kf1 = *(const bf16x8*)(KB + (j * 2 + 1) * 1024 + lane * 16);
      f32x16 sa = __builtin_amdgcn_mfma_f32_32x32x16_bf16(kf0, qf0, zero16, 0, 0, 0);
      sa = __builtin_amdgcn_mfma_f32_32x32x16_bf16(kf1, qf1, sa, 0, 0, 0);

      const bf16_t* bp = bbase + (size_t)j * 64 * 16;
      bf16x8 bv0 = *(const bf16x8*)bp;
      bf16x8 bv1 = *(const bf16x8*)(bp + 8);
#pragma unroll
      for (int r = 0; r < 8; ++r)  sa[r] = __expf(sa[r] + (float)bv0[r]);
#pragma unroll
      for (int r = 8; r < 16; ++r) sa[r] = __expf(sa[r] + (float)bv1[r - 8]);
#pragma unroll
      for (int r = 0; r < 16; ++r) rowsum += sa[r];

      // pack to bf16 pairs (k-order) and half-swap into PV A-fragments
      u32 A0 = pk2(sa[0], sa[1]),   A1 = pk2(sa[2], sa[3]);
      u32 B0 = pk2(sa[4], sa[5]),   B1 = pk2(sa[6], sa[7]);
      u32 C0 = pk2(sa[8], sa[9]),   C1 = pk2(sa[10], sa[11]);
      u32 D0 = pk2(sa[12], sa[13]), D1 = pk2(sa[14], sa[15]);
      u32 w0, w2, w1, w3, y0, y2, y1, y3;
      pswap(A0, B0, w0, w2); pswap(A1, B1, w1, w3);
      pswap(C0, D0, y0, y2); pswap(C1, D1, y1, y3);
      uint4 pa0w = {w0, w1, w2, w3};
      uint4 pa1w = {y0, y1, y2, y3};
      bf16x8 pa0 = __builtin_bit_cast(bf16x8, pa0w);
      bf16x8 pa1 = __builtin_bit_cast(bf16x8, pa1w);

      bf16x8 vf0 = *(const bf16x8*)(VB + (j * 2 + 0) * 1024 + lane * 16);
      bf16x8 vf1 = *(const bf16x8*)(VB + (j * 2 + 1) * 1024 + lane * 16);
      oacc = __builtin_amdgcn_mfma_f32_32x32x16_bf16(pa0, vf0, oacc, 0, 0, 0);
      oacc = __builtin_amdgcn_mfma_f32_32x32x16_bf16(pa1, vf1, oacc, 0, 0, 0);
    }

    // normalize + store
    float rs = rowsum + __shfl_xor(rowsum, 32);
    float inv = 1.f / rs;
#pragma unroll
    for (int r = 0; r < 16; ++r) {
      int rl = (r & 3) + 8 * (r >> 2) + 4 * h;
      float iv = __shfl(inv, rl);
      int row = s * 32 + rl;
      if (row < 294)
        aout[((size_t)b_ * 294 + row) * 256 + hh * 32 + (lane & 31)] =
            (bf16_t)(oacc[r] * iv);
    }
  }
}

// ---------------- K3: output GEMM + inverse permutation (unchanged) ----------------
__global__ __launch_bounds__(256, 2)
void out_gemm(const bf16_t* __restrict__ aout, const bf16_t* __restrict__ wob,
              float* __restrict__ out) {
  __shared__ bf16_t As[2][128][64];
  __shared__ bf16_t Bs[2][128][64];
  const int tid = threadIdx.x, lane = tid & 63, w = tid >> 6;
  const int mt = blockIdx.x >> 1, nt = blockIdx.x & 1;
  const int m0 = mt * 128, n0 = nt * 128;

  const f32x4 zero4 = {0.f, 0.f, 0.f, 0.f};
  f32x4 acc[4][4];
#pragma unroll
  for (int i = 0; i < 4; ++i)
#pragma unroll
    for (int j = 0; j < 4; ++j) acc[i][j] = zero4;

  auto stage = [&](int buf, int kk) {
    const int k0 = kk * 64;
#pragma unroll
    for (int i = 0; i < 4; ++i) {
      int row = w * 32 + i * 8;
      gload16(aout + (size_t)(m0 + row + (lane >> 3)) * 256 + k0 + (lane & 7) * 8,
              &As[buf][row][0]);
      gload16(wob + (size_t)(n0 + row + (lane >> 3)) * 256 + k0 + (lane & 7) * 8,
              &Bs[buf][row][0]);
    }
  };
  auto compute = [&](int buf) {
    const int mb = (w >> 1) * 64, nb = (w & 1) * 64;
#pragma unroll
    for (int ks = 0; ks < 2; ++ks) {
      bf16x8 a[4], bb[4];
#pragma unroll
      for (int i = 0; i < 4; ++i)
        a[i] = *(const bf16x8*)&As[buf][mb + i * 16 + (lane & 15)][ks * 32 + (lane >> 4) * 8];
#pragma unroll
      for (int i = 0; i < 4; ++i)
        bb[i] = *(const bf16x8*)&Bs[buf][nb + i * 16 + (lane & 15)][ks * 32 + (lane >> 4) * 8];
#pragma unroll
      for (int i = 0; i < 4; ++i)
#pragma unroll
        for (int j = 0; j < 4; ++j)
          acc[i][j] = __builtin_amdgcn_mfma_f32_16x16x32_bf16(a[i], bb[j], acc[i][j], 0, 0, 0);
    }
  };

  stage(0, 0);
  __syncthreads();
#pragma unroll
  for (int kk = 0; kk < 4; ++kk) {
    int cur = kk & 1;
    if (kk < 3) stage(cur ^ 1, kk + 1);
    compute(cur);
    __syncthreads();
  }

  const int mb = (w >> 1) * 64, nb = (w & 1) * 64;
#pragma unroll
  for (int i = 0; i < 4; ++i)
#pragma unroll
    for (int r = 0; r < 4; ++r) {
      int R = m0 + mb + i * 16 + (lane >> 4) * 4 + r;
      int b_ = R / 294, n = R - b_ * 294;
      int l = n / 49, p = n - l * 49;
      int X = b_ >> 4, Y = b_ & 15;
      size_t drow = (size_t)(((l * 16 + X) * 16 + Y) * 49 + p) * 256;
#pragma unroll
      for (int j = 0; j < 4; ++j) {
        int col = n0 + nb + j * 16 + (lane & 15);
        out[drow + col] = acc[i][j][r];
      }
    }
}

// ---------------- launch ----------------
extern "C" void kernel_launch(void* const* d_in, const int* in_sizes, int n_in,
                              void* d_out, int out_size, void* d_ws, size_t ws_size,
                              hipStream_t stream) {
  const float* x   = (const float*)d_in[0];
  const float* wq  = (const float*)d_in[1];
  const float* wo  = (const float*)d_in[2];
  const float* bt  = (const float*)d_in[3];
  const int*   ri  = (const int*)d_in[4];
  float* out = (float*)d_out;

  char* ws = (char*)d_ws;
  bf16_t* qkv   = (bf16_t*)(ws);                  // 115,605,504 B
  bf16_t* aoutp = (bf16_t*)(ws + 115605504);      //  38,535,168 B
  bf16_t* wqb   = (bf16_t*)(ws + 154140672);      //     393,216 B
  bf16_t* wob   = (bf16_t*)(ws + 154533888);      //     131,072 B
  bf16_t* biasf = (bf16_t*)(ws + 154664960);      //   1,638,400 B -> total 156,303,360
  if (ws_size < 156303360ULL)
    fprintf(stderr, "WS TOO SMALL: %zu < 156303360\n", ws_size);

  hipLaunchKernelGGL(cvt_weights, dim3(256), dim3(256), 0, stream, wq, wo, wqb, wob);
  hipLaunchKernelGGL(bias_kernel, dim3(3200), dim3(256), 0, stream, bt, ri, biasf);
  hipLaunchKernelGGL(qkv_gemm, dim3(588 * 6), dim3(256), 0, stream, x, wqb, qkv);
  hipLaunchKernelGGL(attn_kernel, dim3(2048), dim3(320), 0, stream, qkv, biasf, aoutp);
  hipLaunchKernelGGL(out_gemm, dim3(588 * 2), dim3(256), 0, stream, aoutp, wob, out);
}

// Round 4
// 304.828 us; speedup vs baseline: 1.3859x; 1.3859x over previous
//
#include <hip/hip_runtime.h>
#include <hip/hip_bf16.h>
#include <cstdio>

typedef __bf16 bf16_t;
typedef __attribute__((ext_vector_type(8))) __bf16 bf16x8;
typedef __attribute__((ext_vector_type(4))) __bf16 bf16x4;
typedef __attribute__((ext_vector_type(2))) __bf16 bf16x2;
typedef __attribute__((ext_vector_type(4))) float f32x4;
typedef __attribute__((ext_vector_type(16))) float f32x16;
typedef unsigned int u32;

#define SCALE 0.17677669529663687f   // 32^-0.5
#define NWIN 294                     // 6*7*7

__device__ __forceinline__ void gload16(const void* g, void* l) {
  __builtin_amdgcn_global_load_lds(
      (const __attribute__((address_space(1))) void*)g,
      (__attribute__((address_space(3))) void*)l, 16, 0, 0);
}

__device__ __forceinline__ u32 pk2(float a, float b) {
  bf16x2 t = {(bf16_t)a, (bf16_t)b};
  return __builtin_bit_cast(u32, t);
}

// half-swap: o0 = [a(lo lanes) | b(lo lanes)], o1 = [a(hi lanes) | b(hi lanes)]
__device__ __forceinline__ void pswap(u32 a, u32 b, u32& o0, u32& o1) {
#if __has_builtin(__builtin_amdgcn_permlane32_swap)
  auto r = __builtin_amdgcn_permlane32_swap(a, b, false, false);
  o0 = (u32)r[0]; o1 = (u32)r[1];
#else
  u32 xa = (u32)__shfl_xor((int)a, 32);
  u32 xb = (u32)__shfl_xor((int)b, 32);
  bool hi = (threadIdx.x & 32) != 0;
  o0 = hi ? xb : a;
  o1 = hi ? b : xa;
#endif
}

// ---------------- K0a: convert weights to bf16 ----------------
__global__ void cvt_weights(const float* __restrict__ wq, const float* __restrict__ wo,
                            bf16_t* __restrict__ wqb, bf16_t* __restrict__ wob) {
  int t = blockIdx.x * 256 + threadIdx.x;
  const int nq4 = 768 * 256 / 4;
  if (t < nq4) {
    float4 v = ((const float4*)wq)[t];
    bf16x4 h = {(bf16_t)v.x, (bf16_t)v.y, (bf16_t)v.z, (bf16_t)v.w};
    ((bf16x4*)wqb)[t] = h;
  } else {
    int t2 = t - nq4;
    float4 v = ((const float4*)wo)[t2];
    bf16x4 h = {(bf16_t)v.x, (bf16_t)v.y, (bf16_t)v.z, (bf16_t)v.w};
    ((bf16x4*)wob)[t2] = h;
  }
}

// ---------------- K0b: bias in 32x32 S^T-fragment layout ----------------
// biasf[h][s][j][lane][r]: value = bias[q = s*32+(lane&31)][k = j*32+(r&3)+8*(r>>2)+4*(lane>>5)]
// col>=294 -> -1e30 (mask), row>=294 -> 0.
__global__ void bias_kernel(const float* __restrict__ bt, const int* __restrict__ ridx,
                            bf16_t* __restrict__ biasf) {
  int t = blockIdx.x * 256 + threadIdx.x;
  if (t >= 8 * 10 * 10 * 64 * 16) return;
  int r = t & 15, lane = (t >> 4) & 63;
  int rest = t >> 10;
  int j = rest % 10; rest /= 10;
  int s = rest % 10; int hh = rest / 10;
  int row = s * 32 + (lane & 31);
  int col = j * 32 + (r & 3) + 8 * (r >> 2) + 4 * (lane >> 5);
  float v;
  if (col >= 294)      v = -1e30f;
  else if (row >= 294) v = 0.f;
  else                 v = bt[ridx[row * 294 + col] * 8 + hh];
  biasf[t] = (bf16_t)v;
}

// ---------------- K1: QKV GEMM (unchanged) ----------------
__global__ __launch_bounds__(256, 2)
void qkv_gemm(const float* __restrict__ x, const bf16_t* __restrict__ wqb,
              bf16_t* __restrict__ qkv) {
  __shared__ bf16_t As[2][128][64];
  __shared__ bf16_t Bs[2][128][64];
  const int tid = threadIdx.x;
  const int lane = tid & 63;
  const int w = tid >> 6;
  const int mt = blockIdx.x / 6, nt = blockIdx.x % 6;
  const int m0 = mt * 128, n0 = nt * 128;
  const int rsub = tid >> 4, csub = (tid & 15) * 4;

  const float* asrc[8];
#pragma unroll
  for (int i = 0; i < 8; ++i) {
    int R = m0 + i * 16 + rsub;
    int b_ = R / 294, n = R - b_ * 294;
    int l = n / 49, p = n - l * 49;
    int X = b_ >> 4, Y = b_ & 15;
    int srow = ((l * 16 + X) * 16 + Y) * 49 + p;
    asrc[i] = x + (size_t)srow * 256 + csub;
  }

  const f32x4 zero4 = {0.f, 0.f, 0.f, 0.f};
  f32x4 acc[4][4];
#pragma unroll
  for (int i = 0; i < 4; ++i)
#pragma unroll
    for (int j = 0; j < 4; ++j) acc[i][j] = zero4;

  auto stageA = [&](int buf, int kk) {
    const int k0 = kk * 64;
#pragma unroll
    for (int i = 0; i < 8; ++i) {
      float4 v = *(const float4*)(asrc[i] + k0);
      bf16x4 h = {(bf16_t)v.x, (bf16_t)v.y, (bf16_t)v.z, (bf16_t)v.w};
      *(bf16x4*)&As[buf][i * 16 + rsub][csub] = h;
    }
  };
  auto stageB = [&](int buf, int kk) {
    const int k0 = kk * 64;
#pragma unroll
    for (int i = 0; i < 4; ++i) {
      int row = w * 32 + i * 8;
      const bf16_t* g = wqb + (size_t)(n0 + row + (lane >> 3)) * 256 + k0 + (lane & 7) * 8;
      gload16(g, &Bs[buf][row][0]);
    }
  };
  auto compute = [&](int buf) {
    const int mb = (w >> 1) * 64, nb = (w & 1) * 64;
#pragma unroll
    for (int ks = 0; ks < 2; ++ks) {
      bf16x8 a[4], bb[4];
#pragma unroll
      for (int i = 0; i < 4; ++i)
        a[i] = *(const bf16x8*)&As[buf][mb + i * 16 + (lane & 15)][ks * 32 + (lane >> 4) * 8];
#pragma unroll
      for (int i = 0; i < 4; ++i)
        bb[i] = *(const bf16x8*)&Bs[buf][nb + i * 16 + (lane & 15)][ks * 32 + (lane >> 4) * 8];
#pragma unroll
      for (int i = 0; i < 4; ++i)
#pragma unroll
        for (int j = 0; j < 4; ++j)
          acc[i][j] = __builtin_amdgcn_mfma_f32_16x16x32_bf16(a[i], bb[j], acc[i][j], 0, 0, 0);
    }
  };

  stageA(0, 0); stageB(0, 0);
  __syncthreads();
#pragma unroll
  for (int kk = 0; kk < 4; ++kk) {
    int cur = kk & 1;
    if (kk < 3) { stageA(cur ^ 1, kk + 1); stageB(cur ^ 1, kk + 1); }
    compute(cur);
    __syncthreads();
  }

  const int mb = (w >> 1) * 64, nb = (w & 1) * 64;
#pragma unroll
  for (int i = 0; i < 4; ++i)
#pragma unroll
    for (int r = 0; r < 4; ++r) {
      int row = m0 + mb + i * 16 + (lane >> 4) * 4 + r;
      size_t rb = (size_t)row * 768;
#pragma unroll
      for (int j = 0; j < 4; ++j) {
        int col = n0 + nb + j * 16 + (lane & 15);
        float sc = (col < 256) ? SCALE : 1.0f;
        qkv[rb + col] = (bf16_t)(acc[i][j][r] * sc);
      }
    }
}

// ---------------- K2: attention, 32x32 MFMA, in-register P ----------------
// LDS: Kf slots 0..19 (slot = j*2+c): lane l holds K[j*32+(l&31)][c*16+(l>>5)*8+e], 16B/lane
//      Vf slots 0..19 (slot = k>>4):  lane l holds V[slot*16+(l>>5)*8+e][d=l&31], 16B/lane
__global__ __launch_bounds__(320, 2)
void attn_kernel(const bf16_t* __restrict__ qkv, const bf16_t* __restrict__ biasf,
                 bf16_t* __restrict__ aout) {
  __shared__ uint4 SMEM4[2560];   // 40960 B
  char* KB = (char*)SMEM4;
  char* VB = KB + 20480;
  const int tid = threadIdx.x, lane = tid & 63, wv = tid >> 6;
  const int h = lane >> 5;
  const int b_ = blockIdx.x >> 3, hh = blockIdx.x & 7;
  const size_t qbase = (size_t)b_ * 294 * 768;
  const uint4 z4 = {0u, 0u, 0u, 0u};

  // ---- zero pads (bytes disjoint from staged bytes) ----
  // K slots 18,19: lanes with (l&31) >= 6  (rows 294..319)
  for (int i = tid; i < 104; i += 320) {
    int sl = 18 + (i >= 52), l2 = i % 52;
    int ln = (l2 < 26) ? (6 + l2) : (38 + (l2 - 26));
    *(uint4*)(KB + sl * 1024 + ln * 16) = z4;
  }
  // V slot 19 full; slot 18 lanes 32..63 full
  for (int i = tid; i < 96; i += 320) {
    int sl = (i < 64) ? 19 : 18;
    int ln = (i < 64) ? i : (32 + (i - 64));
    *(uint4*)(VB + sl * 1024 + ln * 16) = z4;
  }
  // V slot 18 lanes 0..31, bytes 12..15 (k=294,295 -> e=6,7)
  for (int i = tid; i < 32; i += 320)
    *(u32*)(VB + 18 * 1024 + i * 16 + 12) = 0u;

  // ---- stage K via global_load_lds (lane-linear dest) ----
#pragma unroll
  for (int it = 0; it < 4; ++it) {
    int sl = wv * 4 + it;          // wave-uniform
    int j = sl >> 1, c = sl & 1;
    int krow = j * 32 + (lane & 31);
    int q4 = c * 2 + h;
    if (krow < 294)
      gload16(qkv + qbase + (size_t)krow * 768 + 256 + hh * 32 + q4 * 8, KB + sl * 1024);
  }
  // ---- stage V (transpose scatter, one-time) ----
  for (int idx = tid; idx < 1176; idx += 320) {   // 294 rows * 4 chunks
    int k = idx >> 2, q4 = idx & 3;
    uint4 v = *(const uint4*)(qkv + qbase + (size_t)k * 768 + 512 + hh * 32 + q4 * 8);
    const unsigned short* pv = (const unsigned short*)&v;
    int sl = k >> 4;
    char* base = VB + sl * 1024 + ((((k >> 3) & 1) * 32 + q4 * 8) * 16) + (k & 7) * 2;
#pragma unroll
    for (int t = 0; t < 8; ++t)
      *(unsigned short*)(base + t * 16) = pv[t];
  }
  __syncthreads();

  const f32x16 zero16 = {0.f};
  for (int s = wv; s < 10; s += 5) {
    // Q fragment (B-operand): rows s*32..+31, zeroed past 294
    int qrow = s * 32 + (lane & 31);
    bf16x8 qf0 = __builtin_bit_cast(bf16x8, z4), qf1 = qf0;
    if (qrow < 294) {
      const bf16_t* qp = qkv + qbase + (size_t)qrow * 768 + hh * 32 + h * 8;
      qf0 = *(const bf16x8*)qp;
      qf1 = *(const bf16x8*)(qp + 16);
    }

    f32x16 oacc = zero16;
    float rowsum = 0.f;
    const bf16_t* bbase = biasf + (size_t)(((hh * 10 + s) * 10) * 64 + lane) * 16;

#pragma unroll
    for (int j = 0; j < 10; ++j) {
      bf16x8 kf0 = *(const bf16x8*)(KB + (j * 2 + 0) * 1024 + lane * 16);
      bf16x8 kf1 = *(const bf16x8*)(KB + (j * 2 + 1) * 1024 + lane * 16);
      f32x16 sa = __builtin_amdgcn_mfma_f32_32x32x16_bf16(kf0, qf0, zero16, 0, 0, 0);
      sa = __builtin_amdgcn_mfma_f32_32x32x16_bf16(kf1, qf1, sa, 0, 0, 0);

      const bf16_t* bp = bbase + (size_t)j * 64 * 16;
      bf16x8 bv0 = *(const bf16x8*)bp;
      bf16x8 bv1 = *(const bf16x8*)(bp + 8);
#pragma unroll
      for (int r = 0; r < 8; ++r)  sa[r] = __expf(sa[r] + (float)bv0[r]);
#pragma unroll
      for (int r = 8; r < 16; ++r) sa[r] = __expf(sa[r] + (float)bv1[r - 8]);
#pragma unroll
      for (int r = 0; r < 16; ++r) rowsum += sa[r];

      // pack to bf16 pairs (k-order) and half-swap into PV A-fragments
      u32 A0 = pk2(sa[0], sa[1]),   A1 = pk2(sa[2], sa[3]);
      u32 B0 = pk2(sa[4], sa[5]),   B1 = pk2(sa[6], sa[7]);
      u32 C0 = pk2(sa[8], sa[9]),   C1 = pk2(sa[10], sa[11]);
      u32 D0 = pk2(sa[12], sa[13]), D1 = pk2(sa[14], sa[15]);
      u32 w0, w2, w1, w3, y0, y2, y1, y3;
      pswap(A0, B0, w0, w2); pswap(A1, B1, w1, w3);
      pswap(C0, D0, y0, y2); pswap(C1, D1, y1, y3);
      uint4 pa0w = {w0, w1, w2, w3};
      uint4 pa1w = {y0, y1, y2, y3};
      bf16x8 pa0 = __builtin_bit_cast(bf16x8, pa0w);
      bf16x8 pa1 = __builtin_bit_cast(bf16x8, pa1w);

      bf16x8 vf0 = *(const bf16x8*)(VB + (j * 2 + 0) * 1024 + lane * 16);
      bf16x8 vf1 = *(const bf16x8*)(VB + (j * 2 + 1) * 1024 + lane * 16);
      oacc = __builtin_amdgcn_mfma_f32_32x32x16_bf16(pa0, vf0, oacc, 0, 0, 0);
      oacc = __builtin_amdgcn_mfma_f32_32x32x16_bf16(pa1, vf1, oacc, 0, 0, 0);
    }

    // normalize + store
    float rs = rowsum + __shfl_xor(rowsum, 32);
    float inv = 1.f / rs;
#pragma unroll
    for (int r = 0; r < 16; ++r) {
      int rl = (r & 3) + 8 * (r >> 2) + 4 * h;
      float iv = __shfl(inv, rl);
      int row = s * 32 + rl;
      if (row < 294)
        aout[((size_t)b_ * 294 + row) * 256 + hh * 32 + (lane & 31)] =
            (bf16_t)(oacc[r] * iv);
    }
  }
}

// ---------------- K3: output GEMM + inverse permutation (unchanged) ----------------
__global__ __launch_bounds__(256, 2)
void out_gemm(const bf16_t* __restrict__ aout, const bf16_t* __restrict__ wob,
              float* __restrict__ out) {
  __shared__ bf16_t As[2][128][64];
  __shared__ bf16_t Bs[2][128][64];
  const int tid = threadIdx.x, lane = tid & 63, w = tid >> 6;
  const int mt = blockIdx.x >> 1, nt = blockIdx.x & 1;
  const int m0 = mt * 128, n0 = nt * 128;

  const f32x4 zero4 = {0.f, 0.f, 0.f, 0.f};
  f32x4 acc[4][4];
#pragma unroll
  for (int i = 0; i < 4; ++i)
#pragma unroll
    for (int j = 0; j < 4; ++j) acc[i][j] = zero4;

  auto stage = [&](int buf, int kk) {
    const int k0 = kk * 64;
#pragma unroll
    for (int i = 0; i < 4; ++i) {
      int row = w * 32 + i * 8;
      gload16(aout + (size_t)(m0 + row + (lane >> 3)) * 256 + k0 + (lane & 7) * 8,
              &As[buf][row][0]);
      gload16(wob + (size_t)(n0 + row + (lane >> 3)) * 256 + k0 + (lane & 7) * 8,
              &Bs[buf][row][0]);
    }
  };
  auto compute = [&](int buf) {
    const int mb = (w >> 1) * 64, nb = (w & 1) * 64;
#pragma unroll
    for (int ks = 0; ks < 2; ++ks) {
      bf16x8 a[4], bb[4];
#pragma unroll
      for (int i = 0; i < 4; ++i)
        a[i] = *(const bf16x8*)&As[buf][mb + i * 16 + (lane & 15)][ks * 32 + (lane >> 4) * 8];
#pragma unroll
      for (int i = 0; i < 4; ++i)
        bb[i] = *(const bf16x8*)&Bs[buf][nb + i * 16 + (lane & 15)][ks * 32 + (lane >> 4) * 8];
#pragma unroll
      for (int i = 0; i < 4; ++i)
#pragma unroll
        for (int j = 0; j < 4; ++j)
          acc[i][j] = __builtin_amdgcn_mfma_f32_16x16x32_bf16(a[i], bb[j], acc[i][j], 0, 0, 0);
    }
  };

  stage(0, 0);
  __syncthreads();
#pragma unroll
  for (int kk = 0; kk < 4; ++kk) {
    int cur = kk & 1;
    if (kk < 3) stage(cur ^ 1, kk + 1);
    compute(cur);
    __syncthreads();
  }

  const int mb = (w >> 1) * 64, nb = (w & 1) * 64;
#pragma unroll
  for (int i = 0; i < 4; ++i)
#pragma unroll
    for (int r = 0; r < 4; ++r) {
      int R = m0 + mb + i * 16 + (lane >> 4) * 4 + r;
      int b_ = R / 294, n = R - b_ * 294;
      int l = n / 49, p = n - l * 49;
      int X = b_ >> 4, Y = b_ & 15;
      size_t drow = (size_t)(((l * 16 + X) * 16 + Y) * 49 + p) * 256;
#pragma unroll
      for (int j = 0; j < 4; ++j) {
        int col = n0 + nb + j * 16 + (lane & 15);
        out[drow + col] = acc[i][j][r];
      }
    }
}

// ---------------- launch ----------------
extern "C" void kernel_launch(void* const* d_in, const int* in_sizes, int n_in,
                              void* d_out, int out_size, void* d_ws, size_t ws_size,
                              hipStream_t stream) {
  const float* x   = (const float*)d_in[0];
  const float* wq  = (const float*)d_in[1];
  const float* wo  = (const float*)d_in[2];
  const float* bt  = (const float*)d_in[3];
  const int*   ri  = (const int*)d_in[4];
  float* out = (float*)d_out;

  char* ws = (char*)d_ws;
  bf16_t* qkv   = (bf16_t*)(ws);                  // 115,605,504 B
  bf16_t* aoutp = (bf16_t*)(ws + 115605504);      //  38,535,168 B
  bf16_t* wqb   = (bf16_t*)(ws + 154140672);      //     393,216 B
  bf16_t* wob   = (bf16_t*)(ws + 154533888);      //     131,072 B
  bf16_t* biasf = (bf16_t*)(ws + 154664960);      //   1,638,400 B -> total 156,303,360
  if (ws_size < 156303360ULL)
    fprintf(stderr, "WS TOO SMALL: %zu < 156303360\n", ws_size);

  hipLaunchKernelGGL(cvt_weights, dim3(256), dim3(256), 0, stream, wq, wo, wqb, wob);
  hipLaunchKernelGGL(bias_kernel, dim3(3200), dim3(256), 0, stream, bt, ri, biasf);
  hipLaunchKernelGGL(qkv_gemm, dim3(588 * 6), dim3(256), 0, stream, x, wqb, qkv);
  hipLaunchKernelGGL(attn_kernel, dim3(2048), dim3(320), 0, stream, qkv, biasf, aoutp);
  hipLaunchKernelGGL(out_gemm, dim3(588 * 2), dim3(256), 0, stream, aoutp, wob, out);
}

// Round 5
// 294.588 us; speedup vs baseline: 1.4341x; 1.0348x over previous
//
#include <hip/hip_runtime.h>
#include <hip/hip_bf16.h>
#include <cstdio>

typedef __bf16 bf16_t;
typedef __attribute__((ext_vector_type(8))) __bf16 bf16x8;
typedef __attribute__((ext_vector_type(4))) __bf16 bf16x4;
typedef __attribute__((ext_vector_type(2))) __bf16 bf16x2;
typedef __attribute__((ext_vector_type(4))) float f32x4;
typedef __attribute__((ext_vector_type(16))) float f32x16;
typedef unsigned int u32;

#define SCALE 0.17677669529663687f   // 32^-0.5
#define LOG2E 1.44269504088896f
#define NWIN 294                     // 6*7*7

__device__ __forceinline__ void gload16(const void* g, void* l) {
  __builtin_amdgcn_global_load_lds(
      (const __attribute__((address_space(1))) void*)g,
      (__attribute__((address_space(3))) void*)l, 16, 0, 0);
}

__device__ __forceinline__ u32 pk2(float a, float b) {
  bf16x2 t = {(bf16_t)a, (bf16_t)b};
  return __builtin_bit_cast(u32, t);
}

// half-swap: o0 = [a(lo lanes) | b(lo lanes)], o1 = [a(hi lanes) | b(hi lanes)]
__device__ __forceinline__ void pswap(u32 a, u32 b, u32& o0, u32& o1) {
#if __has_builtin(__builtin_amdgcn_permlane32_swap)
  auto r = __builtin_amdgcn_permlane32_swap(a, b, false, false);
  o0 = (u32)r[0]; o1 = (u32)r[1];
#else
  u32 xa = (u32)__shfl_xor((int)a, 32);
  u32 xb = (u32)__shfl_xor((int)b, 32);
  bool hi = (threadIdx.x & 32) != 0;
  o0 = hi ? xb : a;
  o1 = hi ? b : xa;
#endif
}

// ---------------- K0a: convert weights to bf16 ----------------
__global__ void cvt_weights(const float* __restrict__ wq, const float* __restrict__ wo,
                            bf16_t* __restrict__ wqb, bf16_t* __restrict__ wob) {
  int t = blockIdx.x * 256 + threadIdx.x;
  const int nq4 = 768 * 256 / 4;
  if (t < nq4) {
    float4 v = ((const float4*)wq)[t];
    bf16x4 h = {(bf16_t)v.x, (bf16_t)v.y, (bf16_t)v.z, (bf16_t)v.w};
    ((bf16x4*)wqb)[t] = h;
  } else {
    int t2 = t - nq4;
    float4 v = ((const float4*)wo)[t2];
    bf16x4 h = {(bf16_t)v.x, (bf16_t)v.y, (bf16_t)v.z, (bf16_t)v.w};
    ((bf16x4*)wob)[t2] = h;
  }
}

// ---------------- K0b: bias in 32x32 S^T-fragment layout, pre-scaled by log2e ----------------
// biasf[h][s][j][lane][r]: value = log2e * bias[q = s*32+(lane&31)][k = j*32+(r&3)+8*(r>>2)+4*(lane>>5)]
// col>=294 -> -1e30 (mask), row>=294 -> 0.
__global__ void bias_kernel(const float* __restrict__ bt, const int* __restrict__ ridx,
                            bf16_t* __restrict__ biasf) {
  int t = blockIdx.x * 256 + threadIdx.x;
  if (t >= 8 * 10 * 10 * 64 * 16) return;
  int r = t & 15, lane = (t >> 4) & 63;
  int rest = t >> 10;
  int j = rest % 10; rest /= 10;
  int s = rest % 10; int hh = rest / 10;
  int row = s * 32 + (lane & 31);
  int col = j * 32 + (r & 3) + 8 * (r >> 2) + 4 * (lane >> 5);
  float v;
  if (col >= 294)      v = -1e30f;
  else if (row >= 294) v = 0.f;
  else                 v = bt[ridx[row * 294 + col] * 8 + hh] * LOG2E;
  biasf[t] = (bf16_t)v;
}

// ---------------- K1: QKV GEMM ----------------
__global__ __launch_bounds__(256, 2)
void qkv_gemm(const float* __restrict__ x, const bf16_t* __restrict__ wqb,
              bf16_t* __restrict__ qkv) {
  __shared__ bf16_t As[2][128][64];
  __shared__ bf16_t Bs[2][128][64];
  const int tid = threadIdx.x;
  const int lane = tid & 63;
  const int w = tid >> 6;
  const int mt = blockIdx.x / 6, nt = blockIdx.x % 6;
  const int m0 = mt * 128, n0 = nt * 128;
  const int rsub = tid >> 4, csub = (tid & 15) * 4;

  const float* asrc[8];
#pragma unroll
  for (int i = 0; i < 8; ++i) {
    int R = m0 + i * 16 + rsub;
    int b_ = R / 294, n = R - b_ * 294;
    int l = n / 49, p = n - l * 49;
    int X = b_ >> 4, Y = b_ & 15;
    int srow = ((l * 16 + X) * 16 + Y) * 49 + p;
    asrc[i] = x + (size_t)srow * 256 + csub;
  }

  const f32x4 zero4 = {0.f, 0.f, 0.f, 0.f};
  f32x4 acc[4][4];
#pragma unroll
  for (int i = 0; i < 4; ++i)
#pragma unroll
    for (int j = 0; j < 4; ++j) acc[i][j] = zero4;

  auto stageA = [&](int buf, int kk) {
    const int k0 = kk * 64;
#pragma unroll
    for (int i = 0; i < 8; ++i) {
      float4 v = *(const float4*)(asrc[i] + k0);
      bf16x4 h = {(bf16_t)v.x, (bf16_t)v.y, (bf16_t)v.z, (bf16_t)v.w};
      *(bf16x4*)&As[buf][i * 16 + rsub][csub] = h;
    }
  };
  auto stageB = [&](int buf, int kk) {
    const int k0 = kk * 64;
#pragma unroll
    for (int i = 0; i < 4; ++i) {
      int row = w * 32 + i * 8;
      const bf16_t* g = wqb + (size_t)(n0 + row + (lane >> 3)) * 256 + k0 + (lane & 7) * 8;
      gload16(g, &Bs[buf][row][0]);
    }
  };
  auto compute = [&](int buf) {
    const int mb = (w >> 1) * 64, nb = (w & 1) * 64;
#pragma unroll
    for (int ks = 0; ks < 2; ++ks) {
      bf16x8 a[4], bb[4];
#pragma unroll
      for (int i = 0; i < 4; ++i)
        a[i] = *(const bf16x8*)&As[buf][mb + i * 16 + (lane & 15)][ks * 32 + (lane >> 4) * 8];
#pragma unroll
      for (int i = 0; i < 4; ++i)
        bb[i] = *(const bf16x8*)&Bs[buf][nb + i * 16 + (lane & 15)][ks * 32 + (lane >> 4) * 8];
#pragma unroll
      for (int i = 0; i < 4; ++i)
#pragma unroll
        for (int j = 0; j < 4; ++j)
          acc[i][j] = __builtin_amdgcn_mfma_f32_16x16x32_bf16(a[i], bb[j], acc[i][j], 0, 0, 0);
    }
  };

  stageA(0, 0); stageB(0, 0);
  __syncthreads();
#pragma unroll
  for (int kk = 0; kk < 4; ++kk) {
    int cur = kk & 1;
    if (kk < 3) { stageA(cur ^ 1, kk + 1); stageB(cur ^ 1, kk + 1); }
    compute(cur);
    __syncthreads();
  }

  const int mb = (w >> 1) * 64, nb = (w & 1) * 64;
#pragma unroll
  for (int i = 0; i < 4; ++i)
#pragma unroll
    for (int r = 0; r < 4; ++r) {
      int row = m0 + mb + i * 16 + (lane >> 4) * 4 + r;
      size_t rb = (size_t)row * 768;
#pragma unroll
      for (int j = 0; j < 4; ++j) {
        int col = n0 + nb + j * 16 + (lane & 15);
        float sc = (col < 256) ? (SCALE * LOG2E) : 1.0f;   // fold q-scale + log2e
        qkv[rb + col] = (bf16_t)(acc[i][j][r] * sc);
      }
    }
}

// ---------------- K2: attention, 32x32 MFMA, in-register P ----------------
// 128 threads / 2 waves per block; wave wv handles strips s = wv*5 .. wv*5+4 (balanced).
// LDS: Kf slots 0..19 (slot = j*2+c): lane l holds K[j*32+(l&31)][c*16+(l>>5)*8+e], 16B/lane
//      Vf slots 0..19 (slot = k>>4):  lane l holds V[slot*16+(l>>5)*8+e][d=l&31], 16B/lane
__global__ __launch_bounds__(128, 2)
void attn_kernel(const bf16_t* __restrict__ qkv, const bf16_t* __restrict__ biasf,
                 bf16_t* __restrict__ aout) {
  __shared__ uint4 SMEM4[2560];   // 40960 B
  char* KB = (char*)SMEM4;
  char* VB = KB + 20480;
  const int tid = threadIdx.x, lane = tid & 63, wv = tid >> 6;
  const int h = lane >> 5;
  const int b_ = blockIdx.x >> 3, hh = blockIdx.x & 7;
  const size_t qbase = (size_t)b_ * 294 * 768;
  const uint4 z4 = {0u, 0u, 0u, 0u};

  // ---- zero pads (bytes disjoint from staged bytes) ----
  // K slots 18,19: lanes with (l&31) >= 6  (rows 294..319)
  for (int i = tid; i < 104; i += 128) {
    int sl = 18 + (i >= 52), l2 = i % 52;
    int ln = (l2 < 26) ? (6 + l2) : (38 + (l2 - 26));
    *(uint4*)(KB + sl * 1024 + ln * 16) = z4;
  }
  // V slot 19 full; slot 18 lanes 32..63 full
  for (int i = tid; i < 96; i += 128) {
    int sl = (i < 64) ? 19 : 18;
    int ln = (i < 64) ? i : (32 + (i - 64));
    *(uint4*)(VB + sl * 1024 + ln * 16) = z4;
  }
  // V slot 18 lanes 0..31, bytes 12..15 (k=294,295 -> e=6,7)
  for (int i = tid; i < 32; i += 128)
    *(u32*)(VB + 18 * 1024 + i * 16 + 12) = 0u;

  // ---- stage K via global_load_lds (lane-linear dest); 10 slots per wave ----
#pragma unroll
  for (int it = 0; it < 10; ++it) {
    int sl = wv * 10 + it;         // wave-uniform
    int j = sl >> 1, c = sl & 1;
    int krow = j * 32 + (lane & 31);
    int q4 = c * 2 + h;
    if (krow < 294)
      gload16(qkv + qbase + (size_t)krow * 768 + 256 + hh * 32 + q4 * 8, KB + sl * 1024);
  }
  // ---- stage V (transpose scatter, one-time) ----
  for (int idx = tid; idx < 1176; idx += 128) {   // 294 rows * 4 chunks
    int k = idx >> 2, q4 = idx & 3;
    uint4 v = *(const uint4*)(qkv + qbase + (size_t)k * 768 + 512 + hh * 32 + q4 * 8);
    const unsigned short* pv = (const unsigned short*)&v;
    int sl = k >> 4;
    char* base = VB + sl * 1024 + ((((k >> 3) & 1) * 32 + q4 * 8) * 16) + (k & 7) * 2;
#pragma unroll
    for (int t = 0; t < 8; ++t)
      *(unsigned short*)(base + t * 16) = pv[t];
  }
  __syncthreads();

  const f32x16 zero16 = {0.f};
  for (int s = wv * 5; s < wv * 5 + 5; ++s) {
    // Q fragment (B-operand): rows s*32..+31, zeroed past 294
    int qrow = s * 32 + (lane & 31);
    bf16x8 qf0 = __builtin_bit_cast(bf16x8, z4), qf1 = qf0;
    if (qrow < 294) {
      const bf16_t* qp = qkv + qbase + (size_t)qrow * 768 + hh * 32 + h * 8;
      qf0 = *(const bf16x8*)qp;
      qf1 = *(const bf16x8*)(qp + 16);
    }

    f32x16 oacc = zero16;
    float rowsum = 0.f;
    const bf16_t* bbase = biasf + (size_t)(((hh * 10 + s) * 10) * 64 + lane) * 16;

#pragma unroll
    for (int j = 0; j < 10; ++j) {
      bf16x8 kf0 = *(const bf16x8*)(KB + (j * 2 + 0) * 1024 + lane * 16);
      bf16x8 kf1 = *(const bf16x8*)(KB + (j * 2 + 1) * 1024 + lane * 16);
      f32x16 sa = __builtin_amdgcn_mfma_f32_32x32x16_bf16(kf0, qf0, zero16, 0, 0, 0);
      sa = __builtin_amdgcn_mfma_f32_32x32x16_bf16(kf1, qf1, sa, 0, 0, 0);

      const bf16_t* bp = bbase + (size_t)j * 64 * 16;
      bf16x8 bv0 = *(const bf16x8*)bp;
      bf16x8 bv1 = *(const bf16x8*)(bp + 8);
#pragma unroll
      for (int r = 0; r < 8; ++r)  sa[r] = exp2f(sa[r] + (float)bv0[r]);
#pragma unroll
      for (int r = 8; r < 16; ++r) sa[r] = exp2f(sa[r] + (float)bv1[r - 8]);
#pragma unroll
      for (int r = 0; r < 16; ++r) rowsum += sa[r];

      // pack to bf16 pairs (k-order) and half-swap into PV A-fragments
      u32 A0 = pk2(sa[0], sa[1]),   A1 = pk2(sa[2], sa[3]);
      u32 B0 = pk2(sa[4], sa[5]),   B1 = pk2(sa[6], sa[7]);
      u32 C0 = pk2(sa[8], sa[9]),   C1 = pk2(sa[10], sa[11]);
      u32 D0 = pk2(sa[12], sa[13]), D1 = pk2(sa[14], sa[15]);
      u32 w0, w2, w1, w3, y0, y2, y1, y3;
      pswap(A0, B0, w0, w2); pswap(A1, B1, w1, w3);
      pswap(C0, D0, y0, y2); pswap(C1, D1, y1, y3);
      uint4 pa0w = {w0, w1, w2, w3};
      uint4 pa1w = {y0, y1, y2, y3};
      bf16x8 pa0 = __builtin_bit_cast(bf16x8, pa0w);
      bf16x8 pa1 = __builtin_bit_cast(bf16x8, pa1w);

      bf16x8 vf0 = *(const bf16x8*)(VB + (j * 2 + 0) * 1024 + lane * 16);
      bf16x8 vf1 = *(const bf16x8*)(VB + (j * 2 + 1) * 1024 + lane * 16);
      oacc = __builtin_amdgcn_mfma_f32_32x32x16_bf16(pa0, vf0, oacc, 0, 0, 0);
      oacc = __builtin_amdgcn_mfma_f32_32x32x16_bf16(pa1, vf1, oacc, 0, 0, 0);
    }

    // normalize + store
    float rs = rowsum + __shfl_xor(rowsum, 32);
    float inv = 1.f / rs;
#pragma unroll
    for (int r = 0; r < 16; ++r) {
      int rl = (r & 3) + 8 * (r >> 2) + 4 * h;
      float iv = __shfl(inv, rl);
      int row = s * 32 + rl;
      if (row < 294)
        aout[((size_t)b_ * 294 + row) * 256 + hh * 32 + (lane & 31)] =
            (bf16_t)(oacc[r] * iv);
    }
  }
}

// ---------------- K3: output GEMM + inverse permutation ----------------
__global__ __launch_bounds__(256, 2)
void out_gemm(const bf16_t* __restrict__ aout, const bf16_t* __restrict__ wob,
              float* __restrict__ out) {
  __shared__ bf16_t As[2][128][64];
  __shared__ bf16_t Bs[2][128][64];
  const int tid = threadIdx.x, lane = tid & 63, w = tid >> 6;
  const int mt = blockIdx.x >> 1, nt = blockIdx.x & 1;
  const int m0 = mt * 128, n0 = nt * 128;

  const f32x4 zero4 = {0.f, 0.f, 0.f, 0.f};
  f32x4 acc[4][4];
#pragma unroll
  for (int i = 0; i < 4; ++i)
#pragma unroll
    for (int j = 0; j < 4; ++j) acc[i][j] = zero4;

  auto stage = [&](int buf, int kk) {
    const int k0 = kk * 64;
#pragma unroll
    for (int i = 0; i < 4; ++i) {
      int row = w * 32 + i * 8;
      gload16(aout + (size_t)(m0 + row + (lane >> 3)) * 256 + k0 + (lane & 7) * 8,
              &As[buf][row][0]);
      gload16(wob + (size_t)(n0 + row + (lane >> 3)) * 256 + k0 + (lane & 7) * 8,
              &Bs[buf][row][0]);
    }
  };
  auto compute = [&](int buf) {
    const int mb = (w >> 1) * 64, nb = (w & 1) * 64;
#pragma unroll
    for (int ks = 0; ks < 2; ++ks) {
      bf16x8 a[4], bb[4];
#pragma unroll
      for (int i = 0; i < 4; ++i)
        a[i] = *(const bf16x8*)&As[buf][mb + i * 16 + (lane & 15)][ks * 32 + (lane >> 4) * 8];
#pragma unroll
      for (int i = 0; i < 4; ++i)
        bb[i] = *(const bf16x8*)&Bs[buf][nb + i * 16 + (lane & 15)][ks * 32 + (lane >> 4) * 8];
#pragma unroll
      for (int i = 0; i < 4; ++i)
#pragma unroll
        for (int j = 0; j < 4; ++j)
          acc[i][j] = __builtin_amdgcn_mfma_f32_16x16x32_bf16(a[i], bb[j], acc[i][j], 0, 0, 0);
    }
  };

  stage(0, 0);
  __syncthreads();
#pragma unroll
  for (int kk = 0; kk < 4; ++kk) {
    int cur = kk & 1;
    if (kk < 3) stage(cur ^ 1, kk + 1);
    compute(cur);
    __syncthreads();
  }

  const int mb = (w >> 1) * 64, nb = (w & 1) * 64;
#pragma unroll
  for (int i = 0; i < 4; ++i)
#pragma unroll
    for (int r = 0; r < 4; ++r) {
      int R = m0 + mb + i * 16 + (lane >> 4) * 4 + r;
      int b_ = R / 294, n = R - b_ * 294;
      int l = n / 49, p = n - l * 49;
      int X = b_ >> 4, Y = b_ & 15;
      size_t drow = (size_t)(((l * 16 + X) * 16 + Y) * 49 + p) * 256;
#pragma unroll
      for (int j = 0; j < 4; ++j) {
        int col = n0 + nb + j * 16 + (lane & 15);
        out[drow + col] = acc[i][j][r];
      }
    }
}

// ---------------- launch ----------------
extern "C" void kernel_launch(void* const* d_in, const int* in_sizes, int n_in,
                              void* d_out, int out_size, void* d_ws, size_t ws_size,
                              hipStream_t stream) {
  const float* x   = (const float*)d_in[0];
  const float* wq  = (const float*)d_in[1];
  const float* wo  = (const float*)d_in[2];
  const float* bt  = (const float*)d_in[3];
  const int*   ri  = (const int*)d_in[4];
  float* out = (float*)d_out;

  char* ws = (char*)d_ws;
  bf16_t* qkv   = (bf16_t*)(ws);                  // 115,605,504 B
  bf16_t* aoutp = (bf16_t*)(ws + 115605504);      //  38,535,168 B
  bf16_t* wqb   = (bf16_t*)(ws + 154140672);      //     393,216 B
  bf16_t* wob   = (bf16_t*)(ws + 154533888);      //     131,072 B
  bf16_t* biasf = (bf16_t*)(ws + 154664960);      //   1,638,400 B -> total 156,303,360
  if (ws_size < 156303360ULL)
    fprintf(stderr, "WS TOO SMALL: %zu < 156303360\n", ws_size);

  hipLaunchKernelGGL(cvt_weights, dim3(256), dim3(256), 0, stream, wq, wo, wqb, wob);
  hipLaunchKernelGGL(bias_kernel, dim3(3200), dim3(256), 0, stream, bt, ri, biasf);
  hipLaunchKernelGGL(qkv_gemm, dim3(588 * 6), dim3(256), 0, stream, x, wqb, qkv);
  hipLaunchKernelGGL(attn_kernel, dim3(2048), dim3(128), 0, stream, qkv, biasf, aoutp);
  hipLaunchKernelGGL(out_gemm, dim3(588 * 2), dim3(256), 0, stream, aoutp, wob, out);
}